// Round 2
// baseline (1415.928 us; speedup 1.0000x reference)
//
#include <hip/hip_runtime.h>
#include <hip/hip_bf16.h>
#include <stdint.h>

typedef __hip_bfloat16 bf16;
typedef unsigned short ushort_t;

#define B_ 32
#define F_ 4096
#define S_ 8
#define D_ 512
#define H_ 2048
#define LN_EPS 1e-5f
#define EPS_ 1e-8f
#define SCALE_ 0.044194173824159216f  // 512^-0.5

__device__ __forceinline__ float b2f(ushort_t u){
  union { uint32_t i; float f; } c; c.i = ((uint32_t)u) << 16; return c.f;
}
__device__ __forceinline__ float4 ld4f(const float* p){ return *(const float4*)p; }
__device__ __forceinline__ float4 ld4h(const ushort_t* p){
  ushort4 u = *(const ushort4*)p;
  return make_float4(b2f(u.x), b2f(u.y), b2f(u.z), b2f(u.w));
}
__device__ __forceinline__ float allsum64(float v){
  #pragma unroll
  for (int o = 1; o < 64; o <<= 1) v += __shfl_xor(v, o, 64);
  return v;
}
__device__ __forceinline__ float blockSum256(float v, float* sh){
  v = allsum64(v);
  int wid = threadIdx.x >> 6, lane = threadIdx.x & 63;
  __syncthreads();
  if (lane == 0) sh[wid] = v;
  __syncthreads();
  return sh[0] + sh[1] + sh[2] + sh[3];
}

// flag=1 -> tensors are fp32; flag=0 -> bf16. Detected from bit patterns of
// `features`: for genuine bf16 pairs the low half of each 32-bit word is a
// bf16 from ~N(0,1) (exponent in [~100,130]); for fp32 data it is random
// mantissa bits (exponent uniform -> ~26% land at 0 or >=0xBF).
__global__ void detect_dtype(const uint32_t* __restrict__ w, int* __restrict__ flag){
  __shared__ int sh;
  if (threadIdx.x == 0) sh = 0;
  __syncthreads();
  int c = 0;
  for (int i = threadIdx.x; i < 4096; i += 256){
    uint32_t e = (w[i] >> 7) & 0xFF;
    if (e == 0 || e >= 0xBF) c++;
  }
  atomicAdd(&sh, c);
  __syncthreads();
  if (threadIdx.x == 0) *flag = (sh >= 100) ? 1 : 0;
}

template<int TRANS_B, int BIAS, int RELU, int A_DYN, int B_DYN>
__global__ __launch_bounds__(256) void gemm64(
    const void* __restrict__ A, const void* __restrict__ B,
    const void* __restrict__ bias, float* __restrict__ C,
    int M, int N, int K, int kLen, const int* __restrict__ flag)
{
  const bool f32 = (*flag != 0);
  const bool aF = A_DYN ? f32 : true;
  const bool bF = B_DYN ? f32 : true;
  __shared__ float As[16][68];
  __shared__ float Bs[16][68];
  const int tid = threadIdx.x;
  const int m0 = blockIdx.x * 64, n0 = blockIdx.y * 64;
  const int kBeg = blockIdx.z * kLen;
  const int tm = (tid & 15) * 4, tn = (tid >> 4) * 4;
  const int ar = tid >> 2;
  const int ac = (tid & 3) * 4;
  const int br = tid >> 4;
  const int bc = (tid & 15) * 4;
  float acc[4][4] = {};

  for (int kc = kBeg; kc < kBeg + kLen; kc += 16){
    size_t aidx = (size_t)(m0 + ar) * K + kc + ac;
    float4 a4 = aF ? ld4f((const float*)A + aidx) : ld4h((const ushort_t*)A + aidx);
    As[ac+0][ar] = a4.x; As[ac+1][ar] = a4.y; As[ac+2][ar] = a4.z; As[ac+3][ar] = a4.w;
    if (!TRANS_B){
      size_t bidx = (size_t)(kc + br) * N + n0 + bc;
      float4 b4 = bF ? ld4f((const float*)B + bidx) : ld4h((const ushort_t*)B + bidx);
      Bs[br][bc+0] = b4.x; Bs[br][bc+1] = b4.y; Bs[br][bc+2] = b4.z; Bs[br][bc+3] = b4.w;
    } else {
      size_t bidx = (size_t)(n0 + ar) * K + kc + ac;
      float4 b4 = bF ? ld4f((const float*)B + bidx) : ld4h((const ushort_t*)B + bidx);
      Bs[ac+0][ar] = b4.x; Bs[ac+1][ar] = b4.y; Bs[ac+2][ar] = b4.z; Bs[ac+3][ar] = b4.w;
    }
    __syncthreads();
    #pragma unroll
    for (int k = 0; k < 16; k++){
      float av[4], bv[4];
      #pragma unroll
      for (int i = 0; i < 4; i++) av[i] = As[k][tm + i];
      #pragma unroll
      for (int j = 0; j < 4; j++) bv[j] = Bs[k][tn + j];
      #pragma unroll
      for (int i = 0; i < 4; i++)
        #pragma unroll
        for (int j = 0; j < 4; j++) acc[i][j] += av[i] * bv[j];
    }
    __syncthreads();
  }
  float bb[4] = {0,0,0,0};
  if (BIAS){
    #pragma unroll
    for (int j = 0; j < 4; j++)
      bb[j] = f32 ? ((const float*)bias)[n0 + tn + j]
                  : b2f(((const ushort_t*)bias)[n0 + tn + j]);
  }
  #pragma unroll
  for (int i = 0; i < 4; i++){
    #pragma unroll
    for (int j = 0; j < 4; j++){
      float v = acc[i][j];
      if (BIAS) v += bb[j];
      if (RELU) v = fmaxf(v, 0.0f);
      C[((size_t)blockIdx.z * M + m0 + tm + i) * N + n0 + tn + j] = v;
    }
  }
}

// attn_out is passed as d_out base; the correct 131072-element offset is
// applied inside with the dtype-correct element size.
template<int F32>
__global__ __launch_bounds__(256, 2) void big_pass(
    const void* __restrict__ features, const float* __restrict__ qk,
    const void* __restrict__ lnw, const void* __restrict__ lnb,
    void* __restrict__ d_out_base, float* __restrict__ Upart,
    float* __restrict__ Rpart, const int* __restrict__ flag)
{
  if ((*flag != 0) != (F32 != 0)) return;
  __shared__ float Ubuf[4][S_ * D_];
  __shared__ float Rbuf[4][S_];
  __shared__ float pbuf[S_][256];
  const int b = blockIdx.y;
  const int tid = threadIdx.x;
  const int wid = tid >> 6, lane = tid & 63;
  const int fblock = blockIdx.x * 256;
  const int f0 = fblock + wid * 64;

  float lw[8], lb[8];
  #pragma unroll
  for (int j = 0; j < 8; j++){
    int d = 8 * lane + j;
    lw[j] = F32 ? ((const float*)lnw)[d] : b2f(((const ushort_t*)lnw)[d]);
    lb[j] = F32 ? ((const float*)lnb)[d] : b2f(((const ushort_t*)lnb)[d]);
  }
  float qkr[8][8];
  #pragma unroll
  for (int s = 0; s < 8; s++){
    const float* qp = qk + (size_t)(b * S_ + s) * D_ + 8 * lane;
    float4 q0 = *(const float4*)qp;
    float4 q1 = *(const float4*)(qp + 4);
    qkr[s][0]=q0.x; qkr[s][1]=q0.y; qkr[s][2]=q0.z; qkr[s][3]=q0.w;
    qkr[s][4]=q1.x; qkr[s][5]=q1.y; qkr[s][6]=q1.z; qkr[s][7]=q1.w;
  }
  float U[8][8];
  #pragma unroll
  for (int s = 0; s < 8; s++)
    #pragma unroll
    for (int j = 0; j < 8; j++) U[s][j] = 0.0f;
  float racc[8] = {0,0,0,0,0,0,0,0};

  const size_t base = ((size_t)b * F_ + f0) * D_ + 8 * lane;
  const float* fbf = (const float*)features + base;
  const ushort_t* fbh = (const ushort_t*)features + base;
  float4 nf0 = {}, nf1 = {}; uint4 nh = {};
  if (F32){ nf0 = *(const float4*)fbf; nf1 = *(const float4*)(fbf + 4); }
  else    { nh  = *(const uint4*)fbh; }

  for (int r = 0; r < 64; r++){
    float x[8];
    if (F32){
      float4 c0 = nf0, c1 = nf1;
      if (r < 63){
        nf0 = *(const float4*)(fbf + (size_t)(r + 1) * D_);
        nf1 = *(const float4*)(fbf + (size_t)(r + 1) * D_ + 4);
      }
      x[0]=c0.x; x[1]=c0.y; x[2]=c0.z; x[3]=c0.w;
      x[4]=c1.x; x[5]=c1.y; x[6]=c1.z; x[7]=c1.w;
    } else {
      uint4 cx = nh;
      if (r < 63) nh = *(const uint4*)(fbh + (size_t)(r + 1) * D_);
      x[0]=b2f(cx.x & 0xffff); x[1]=b2f(cx.x >> 16);
      x[2]=b2f(cx.y & 0xffff); x[3]=b2f(cx.y >> 16);
      x[4]=b2f(cx.z & 0xffff); x[5]=b2f(cx.z >> 16);
      x[6]=b2f(cx.w & 0xffff); x[7]=b2f(cx.w >> 16);
    }
    float sum = 0.0f;
    #pragma unroll
    for (int j = 0; j < 8; j++) sum += x[j];
    float mean = allsum64(sum) * (1.0f / 512.0f);
    float var = 0.0f;
    #pragma unroll
    for (int j = 0; j < 8; j++){ x[j] -= mean; var += x[j] * x[j]; }
    var = allsum64(var) * (1.0f / 512.0f);
    float rstd = 1.0f / sqrtf(var + LN_EPS);
    float y[8];
    #pragma unroll
    for (int j = 0; j < 8; j++) y[j] = x[j] * rstd * lw[j] + lb[j];

    float dt[8];
    #pragma unroll
    for (int s = 0; s < 8; s++){
      float t = 0.0f;
      #pragma unroll
      for (int j = 0; j < 8; j++) t += qkr[s][j] * y[j];
      dt[s] = allsum64(t) * SCALE_;
    }
    float mx = dt[0];
    #pragma unroll
    for (int s = 1; s < 8; s++) mx = fmaxf(mx, dt[s]);
    float p[8]; float den = 0.0f;
    #pragma unroll
    for (int s = 0; s < 8; s++){ p[s] = __expf(dt[s] - mx); den += p[s]; }
    float inv = 1.0f / den;
    #pragma unroll
    for (int s = 0; s < 8; s++) p[s] *= inv;
    #pragma unroll
    for (int s = 0; s < 8; s++) if (lane == s) pbuf[s][wid * 64 + r] = p[s];
    #pragma unroll
    for (int s = 0; s < 8; s++){
      float pe = p[s] + EPS_;
      racc[s] += pe;
      #pragma unroll
      for (int j = 0; j < 8; j++) U[s][j] += pe * y[j];
    }
  }
  #pragma unroll
  for (int s = 0; s < 8; s++){
    float* ub = &Ubuf[wid][s * D_ + 8 * lane];
    *(float4*)ub     = make_float4(U[s][0], U[s][1], U[s][2], U[s][3]);
    *(float4*)(ub+4) = make_float4(U[s][4], U[s][5], U[s][6], U[s][7]);
  }
  #pragma unroll
  for (int s = 0; s < 8; s++) if (lane == s) Rbuf[wid][s] = racc[s];
  __syncthreads();
  float* up = Upart + (size_t)(b * 16 + blockIdx.x) * S_ * D_;
  for (int e = tid; e < S_ * D_; e += 256)
    up[e] = Ubuf[0][e] + Ubuf[1][e] + Ubuf[2][e] + Ubuf[3][e];
  if (tid < 8)
    Rpart[(b * 16 + blockIdx.x) * S_ + tid] =
        Rbuf[0][tid] + Rbuf[1][tid] + Rbuf[2][tid] + Rbuf[3][tid];
  #pragma unroll
  for (int s = 0; s < 8; s++){
    size_t oi = 131072 + ((size_t)(b * S_ + s)) * F_ + fblock + tid;
    float pv = pbuf[s][tid];
    if (F32) ((float*)d_out_base)[oi] = pv;
    else     ((bf16*)d_out_base)[oi] = __float2bfloat16(pv);
  }
}

__global__ __launch_bounds__(256) void reduce_updates(
    const float* __restrict__ Upart, const float* __restrict__ Rpart,
    float* __restrict__ Ud)
{
  __shared__ float rinv;
  int bs = blockIdx.x;
  int b = bs >> 3, s = bs & 7;
  int t = threadIdx.x;
  if (t == 0){
    float r = 0.0f;
    for (int w = 0; w < 16; w++) r += Rpart[(b * 16 + w) * S_ + s];
    rinv = 1.0f / r;
  }
  __syncthreads();
  const float* up = Upart + ((size_t)(b * 16) * S_ + s) * D_;
  float ri = rinv;
  #pragma unroll
  for (int u = 0; u < 2; u++){
    int e = t + u * 256;
    float acc = 0.0f;
    for (int w = 0; w < 16; w++) acc += up[(size_t)w * S_ * D_ + e];
    Ud[((size_t)(b * S_ + s)) * D_ + e] = acc * ri;
  }
}

__global__ __launch_bounds__(256) void ln_rows(
    const float* __restrict__ x, const void* __restrict__ w,
    const void* __restrict__ b, float* __restrict__ y, const int* __restrict__ flag)
{
  const bool f32 = (*flag != 0);
  __shared__ float sh[4];
  int row = blockIdx.x, t = threadIdx.x;
  const float* xr = x + (size_t)row * D_;
  float v0 = xr[t], v1 = xr[t + 256];
  float mean = blockSum256(v0 + v1, sh) * (1.0f / 512.0f);
  float d0 = v0 - mean, d1 = v1 - mean;
  float var = blockSum256(d0 * d0 + d1 * d1, sh) * (1.0f / 512.0f);
  float rstd = 1.0f / sqrtf(var + LN_EPS);
  float w0 = f32 ? ((const float*)w)[t]       : b2f(((const ushort_t*)w)[t]);
  float w1 = f32 ? ((const float*)w)[t + 256] : b2f(((const ushort_t*)w)[t + 256]);
  float b0 = f32 ? ((const float*)b)[t]       : b2f(((const ushort_t*)b)[t]);
  float b1 = f32 ? ((const float*)b)[t + 256] : b2f(((const ushort_t*)b)[t + 256]);
  y[(size_t)row * D_ + t]       = d0 * rstd * w0 + b0;
  y[(size_t)row * D_ + t + 256] = d1 * rstd * w1 + b1;
}

__global__ __launch_bounds__(256) void gru_gate_ln(
    const float* __restrict__ gi, const float* __restrict__ gh,
    const float* __restrict__ sn, const void* __restrict__ lw,
    const void* __restrict__ lb, float* __restrict__ snew,
    float* __restrict__ lnm, const int* __restrict__ flag)
{
  const bool f32 = (*flag != 0);
  __shared__ float sh[4];
  int row = blockIdx.x, t = threadIdx.x;
  const float* gir = gi + (size_t)row * 1536;
  const float* ghr = gh + (size_t)row * 1536;
  const float* snr = sn + (size_t)row * D_;
  float v[2];
  #pragma unroll
  for (int u = 0; u < 2; u++){
    int d = t + u * 256;
    float ir = gir[d], iz = gir[512 + d], in_ = gir[1024 + d];
    float hr = ghr[d], hz = ghr[512 + d], hn = ghr[1024 + d];
    float rg = 1.0f / (1.0f + __expf(-(ir + hr)));
    float zg = 1.0f / (1.0f + __expf(-(iz + hz)));
    float a  = in_ + rg * hn;
    float e2 = __expf(2.0f * a);
    float ng = 1.0f - 2.0f / (e2 + 1.0f);
    float h  = snr[d];
    v[u] = (1.0f - zg) * ng + zg * h;
    snew[(size_t)row * D_ + d] = v[u];
  }
  float mean = blockSum256(v[0] + v[1], sh) * (1.0f / 512.0f);
  float d0 = v[0] - mean, d1 = v[1] - mean;
  float var = blockSum256(d0 * d0 + d1 * d1, sh) * (1.0f / 512.0f);
  float rstd = 1.0f / sqrtf(var + LN_EPS);
  float w0 = f32 ? ((const float*)lw)[t]       : b2f(((const ushort_t*)lw)[t]);
  float w1 = f32 ? ((const float*)lw)[t + 256] : b2f(((const ushort_t*)lw)[t + 256]);
  float b0 = f32 ? ((const float*)lb)[t]       : b2f(((const ushort_t*)lb)[t]);
  float b1 = f32 ? ((const float*)lb)[t + 256] : b2f(((const ushort_t*)lb)[t + 256]);
  lnm[(size_t)row * D_ + t]       = d0 * rstd * w0 + b0;
  lnm[(size_t)row * D_ + t + 256] = d1 * rstd * w1 + b1;
}

__global__ __launch_bounds__(256) void combine_h2(
    const float* __restrict__ snew, const float* __restrict__ h2p,
    const void* __restrict__ b2, float* __restrict__ slots,
    const int* __restrict__ flag)
{
  const bool f32 = (*flag != 0);
  int idx = blockIdx.x * 256 + threadIdx.x;
  int d = idx & 511;
  float bias = f32 ? ((const float*)b2)[d] : b2f(((const ushort_t*)b2)[d]);
  slots[idx] = snew[idx] + h2p[idx] + h2p[131072 + idx] + h2p[262144 + idx]
             + h2p[393216 + idx] + bias;
}

__global__ __launch_bounds__(256) void cast_in(const void* __restrict__ in,
                                               float* __restrict__ out,
                                               const int* __restrict__ flag){
  const bool f32 = (*flag != 0);
  int i = blockIdx.x * 256 + threadIdx.x;
  out[i] = f32 ? ((const float*)in)[i] : b2f(((const ushort_t*)in)[i]);
}
__global__ __launch_bounds__(256) void store_out(const float* __restrict__ in,
                                                 void* __restrict__ out,
                                                 const int* __restrict__ flag){
  const bool f32 = (*flag != 0);
  int i = blockIdx.x * 256 + threadIdx.x;
  float v = in[i];
  if (f32) ((float*)out)[i] = v;
  else     ((bf16*)out)[i] = __float2bfloat16(v);
}

extern "C" void kernel_launch(void* const* d_in, const int* in_sizes, int n_in,
                              void* d_out, int out_size, void* d_ws, size_t ws_size,
                              hipStream_t stream)
{
  const void* in_slots  = d_in[0];
  const void* features  = d_in[1];
  const void* w_k   = d_in[2];
  const void* w_v   = d_in[3];
  const void* w_q   = d_in[4];
  const void* ln_feat_w = d_in[5];
  const void* ln_feat_b = d_in[6];
  const void* ln_slot_w = d_in[7];
  const void* ln_slot_b = d_in[8];
  const void* w_ih  = d_in[9];
  const void* w_hh  = d_in[10];
  const void* b_ih  = d_in[11];
  const void* b_hh  = d_in[12];
  const void* ln_mlp_w = d_in[13];
  const void* ln_mlp_b = d_in[14];
  const void* mlp_w1 = d_in[15];
  const void* mlp_b1 = d_in[16];
  const void* mlp_w2 = d_in[17];
  const void* mlp_b2 = d_in[18];

  float* W     = (float*)d_ws;
  int*   flag  = (int*)d_ws;
  float* Wqk   = W + 64;
  float* slots = Wqk + 262144;
  float* s_n   = slots + 131072;
  float* qkb   = s_n + 131072;
  float* Ud    = qkb + 131072;
  float* upd   = Ud + 131072;
  float* Rpart = upd + 131072;
  float* P     = Rpart + 4096;     // union region (2097152 floats)
  float* Upart = P;                // dead after reduce_updates
  float* gi    = P;
  float* gh    = P + 393216;
  float* lnm   = P + 786432;
  float* snew  = P + 917504;
  float* h1    = P + 1048576;
  float* h2p   = P + 1572864;

  detect_dtype<<<1, 256, 0, stream>>>((const uint32_t*)features, flag);
  cast_in<<<512, 256, 0, stream>>>(in_slots, slots, flag);
  gemm64<1, 0, 0, 1, 1><<<dim3(8, 8, 1), 256, 0, stream>>>(
      w_q, w_k, nullptr, Wqk, 512, 512, 512, 512, flag);

  for (int it = 0; it < 3; ++it){
    ln_rows<<<256, 256, 0, stream>>>(slots, ln_slot_w, ln_slot_b, s_n, flag);
    gemm64<0, 0, 0, 0, 0><<<dim3(4, 8, 1), 256, 0, stream>>>(
        s_n, Wqk, nullptr, qkb, 256, 512, 512, 512, flag);
    big_pass<0><<<dim3(16, 32), 256, 0, stream>>>(
        features, qkb, ln_feat_w, ln_feat_b, d_out, Upart, Rpart, flag);
    big_pass<1><<<dim3(16, 32), 256, 0, stream>>>(
        features, qkb, ln_feat_w, ln_feat_b, d_out, Upart, Rpart, flag);
    reduce_updates<<<256, 256, 0, stream>>>(Upart, Rpart, Ud);
    gemm64<0, 0, 0, 0, 1><<<dim3(4, 8, 1), 256, 0, stream>>>(
        Ud, w_v, nullptr, upd, 256, 512, 512, 512, flag);
    gemm64<1, 1, 0, 0, 1><<<dim3(4, 24, 1), 256, 0, stream>>>(
        upd, w_ih, b_ih, gi, 256, 1536, 512, 512, flag);
    gemm64<1, 1, 0, 0, 1><<<dim3(4, 24, 1), 256, 0, stream>>>(
        s_n, w_hh, b_hh, gh, 256, 1536, 512, 512, flag);
    gru_gate_ln<<<256, 256, 0, stream>>>(gi, gh, s_n, ln_mlp_w, ln_mlp_b,
                                         snew, lnm, flag);
    gemm64<0, 1, 1, 0, 1><<<dim3(4, 32, 1), 256, 0, stream>>>(
        lnm, mlp_w1, mlp_b1, h1, 256, 2048, 512, 512, flag);
    gemm64<0, 0, 0, 0, 1><<<dim3(4, 8, 4), 256, 0, stream>>>(
        h1, mlp_w2, nullptr, h2p, 256, 512, 2048, 512, flag);
    combine_h2<<<512, 256, 0, stream>>>(snew, h2p, mlp_b2, slots, flag);
  }
  store_out<<<512, 256, 0, stream>>>(slots, d_out, flag);
}

// Round 5
// 1097.204 us; speedup vs baseline: 1.2905x; 1.2905x over previous
//
#include <hip/hip_runtime.h>
#include <hip/hip_bf16.h>
#include <stdint.h>

typedef __hip_bfloat16 bf16;
typedef unsigned short ushort_t;

#define B_ 32
#define F_ 4096
#define S_ 8
#define D_ 512
#define H_ 2048
#define LN_EPS 1e-5f
#define EPS_ 1e-8f
#define SCALE_ 0.044194173824159216f  // 512^-0.5

__device__ __forceinline__ float b2f(ushort_t u){
  union { uint32_t i; float f; } c; c.i = ((uint32_t)u) << 16; return c.f;
}
__device__ __forceinline__ float4 ld4f(const float* p){ return *(const float4*)p; }
__device__ __forceinline__ float4 ld4h(const ushort_t* p){
  ushort4 u = *(const ushort4*)p;
  return make_float4(b2f(u.x), b2f(u.y), b2f(u.z), b2f(u.w));
}
__device__ __forceinline__ float allsum64(float v){
  #pragma unroll
  for (int o = 1; o < 64; o <<= 1) v += __shfl_xor(v, o, 64);
  return v;
}
__device__ __forceinline__ float blockSum256(float v, float* sh){
  v = allsum64(v);
  int wid = threadIdx.x >> 6, lane = threadIdx.x & 63;
  __syncthreads();
  if (lane == 0) sh[wid] = v;
  __syncthreads();
  return sh[0] + sh[1] + sh[2] + sh[3];
}

// flag=1 -> tensors are fp32; flag=0 -> bf16. Detected from bit patterns of
// `features`: for genuine bf16 pairs the low half of each 32-bit word is a
// bf16 from ~N(0,1) (exponent in [~100,130]); for fp32 data it is random
// mantissa bits (exponent uniform -> ~26% land at 0 or >=0xBF).
__global__ void detect_dtype(const uint32_t* __restrict__ w, int* __restrict__ flag){
  __shared__ int sh;
  if (threadIdx.x == 0) sh = 0;
  __syncthreads();
  int c = 0;
  for (int i = threadIdx.x; i < 4096; i += 256){
    uint32_t e = (w[i] >> 7) & 0xFF;
    if (e == 0 || e >= 0xBF) c++;
  }
  atomicAdd(&sh, c);
  __syncthreads();
  if (threadIdx.x == 0) *flag = (sh >= 100) ? 1 : 0;
}

template<int TRANS_B, int BIAS, int RELU, int A_DYN, int B_DYN>
__global__ __launch_bounds__(256) void gemm64(
    const void* __restrict__ A, const void* __restrict__ B,
    const void* __restrict__ bias, float* __restrict__ C,
    int M, int N, int K, int kLen, const int* __restrict__ flag)
{
  const bool f32 = (*flag != 0);
  const bool aF = A_DYN ? f32 : true;
  const bool bF = B_DYN ? f32 : true;
  __shared__ float As[16][68];
  __shared__ float Bs[16][68];
  const int tid = threadIdx.x;
  const int m0 = blockIdx.x * 64, n0 = blockIdx.y * 64;
  const int kBeg = blockIdx.z * kLen;
  const int tm = (tid & 15) * 4, tn = (tid >> 4) * 4;
  const int ar = tid >> 2;
  const int ac = (tid & 3) * 4;
  const int br = tid >> 4;
  const int bc = (tid & 15) * 4;
  float acc[4][4] = {};

  for (int kc = kBeg; kc < kBeg + kLen; kc += 16){
    size_t aidx = (size_t)(m0 + ar) * K + kc + ac;
    float4 a4 = aF ? ld4f((const float*)A + aidx) : ld4h((const ushort_t*)A + aidx);
    As[ac+0][ar] = a4.x; As[ac+1][ar] = a4.y; As[ac+2][ar] = a4.z; As[ac+3][ar] = a4.w;
    if (!TRANS_B){
      size_t bidx = (size_t)(kc + br) * N + n0 + bc;
      float4 b4 = bF ? ld4f((const float*)B + bidx) : ld4h((const ushort_t*)B + bidx);
      Bs[br][bc+0] = b4.x; Bs[br][bc+1] = b4.y; Bs[br][bc+2] = b4.z; Bs[br][bc+3] = b4.w;
    } else {
      size_t bidx = (size_t)(n0 + ar) * K + kc + ac;
      float4 b4 = bF ? ld4f((const float*)B + bidx) : ld4h((const ushort_t*)B + bidx);
      Bs[ac+0][ar] = b4.x; Bs[ac+1][ar] = b4.y; Bs[ac+2][ar] = b4.z; Bs[ac+3][ar] = b4.w;
    }
    __syncthreads();
    #pragma unroll
    for (int k = 0; k < 16; k++){
      float av[4], bv[4];
      #pragma unroll
      for (int i = 0; i < 4; i++) av[i] = As[k][tm + i];
      #pragma unroll
      for (int j = 0; j < 4; j++) bv[j] = Bs[k][tn + j];
      #pragma unroll
      for (int i = 0; i < 4; i++)
        #pragma unroll
        for (int j = 0; j < 4; j++) acc[i][j] += av[i] * bv[j];
    }
    __syncthreads();
  }
  float bb[4] = {0,0,0,0};
  if (BIAS){
    #pragma unroll
    for (int j = 0; j < 4; j++)
      bb[j] = f32 ? ((const float*)bias)[n0 + tn + j]
                  : b2f(((const ushort_t*)bias)[n0 + tn + j]);
  }
  #pragma unroll
  for (int i = 0; i < 4; i++){
    #pragma unroll
    for (int j = 0; j < 4; j++){
      float v = acc[i][j];
      if (BIAS) v += bb[j];
      if (RELU) v = fmaxf(v, 0.0f);
      C[((size_t)blockIdx.z * M + m0 + tm + i) * N + n0 + tn + j] = v;
    }
  }
}

// NEW in round 5: sum 4 split-K partials (+optional bf16 bias, +relu).
// out[i] = act(in[i] + in[sz+i] + in[2sz+i] + in[3sz+i] + bias[i % N])
template<int BIAS, int RELU>
__global__ __launch_bounds__(256) void combine4(
    const float* __restrict__ in, const void* __restrict__ bias,
    float* __restrict__ out, int sz, int N)
{
  int i = blockIdx.x * 256 + threadIdx.x;
  float v = in[i] + in[sz + i] + in[2 * sz + i] + in[3 * sz + i];
  if (BIAS) v += b2f(((const ushort_t*)bias)[i % N]);
  if (RELU) v = fmaxf(v, 0.0f);
  out[i] = v;
}

// attn_out is passed as d_out base; the correct 131072-element offset is
// applied inside with the dtype-correct element size.
template<int F32>
__global__ __launch_bounds__(256, 2) void big_pass(
    const void* __restrict__ features, const float* __restrict__ qk,
    const void* __restrict__ lnw, const void* __restrict__ lnb,
    void* __restrict__ d_out_base, float* __restrict__ Upart,
    float* __restrict__ Rpart, const int* __restrict__ flag)
{
  if ((*flag != 0) != (F32 != 0)) return;
  __shared__ float Ubuf[4][S_ * D_];
  __shared__ float Rbuf[4][S_];
  __shared__ float pbuf[S_][256];
  const int b = blockIdx.y;
  const int tid = threadIdx.x;
  const int wid = tid >> 6, lane = tid & 63;
  const int fblock = blockIdx.x * 256;
  const int f0 = fblock + wid * 64;

  float lw[8], lb[8];
  #pragma unroll
  for (int j = 0; j < 8; j++){
    int d = 8 * lane + j;
    lw[j] = F32 ? ((const float*)lnw)[d] : b2f(((const ushort_t*)lnw)[d]);
    lb[j] = F32 ? ((const float*)lnb)[d] : b2f(((const ushort_t*)lnb)[d]);
  }
  float qkr[8][8];
  #pragma unroll
  for (int s = 0; s < 8; s++){
    const float* qp = qk + (size_t)(b * S_ + s) * D_ + 8 * lane;
    float4 q0 = *(const float4*)qp;
    float4 q1 = *(const float4*)(qp + 4);
    qkr[s][0]=q0.x; qkr[s][1]=q0.y; qkr[s][2]=q0.z; qkr[s][3]=q0.w;
    qkr[s][4]=q1.x; qkr[s][5]=q1.y; qkr[s][6]=q1.z; qkr[s][7]=q1.w;
  }
  float U[8][8];
  #pragma unroll
  for (int s = 0; s < 8; s++)
    #pragma unroll
    for (int j = 0; j < 8; j++) U[s][j] = 0.0f;
  float racc[8] = {0,0,0,0,0,0,0,0};

  const size_t base = ((size_t)b * F_ + f0) * D_ + 8 * lane;
  const float* fbf = (const float*)features + base;
  const ushort_t* fbh = (const ushort_t*)features + base;
  float4 nf0 = {}, nf1 = {}; uint4 nh = {};
  if (F32){ nf0 = *(const float4*)fbf; nf1 = *(const float4*)(fbf + 4); }
  else    { nh  = *(const uint4*)fbh; }

  for (int r = 0; r < 64; r++){
    float x[8];
    if (F32){
      float4 c0 = nf0, c1 = nf1;
      if (r < 63){
        nf0 = *(const float4*)(fbf + (size_t)(r + 1) * D_);
        nf1 = *(const float4*)(fbf + (size_t)(r + 1) * D_ + 4);
      }
      x[0]=c0.x; x[1]=c0.y; x[2]=c0.z; x[3]=c0.w;
      x[4]=c1.x; x[5]=c1.y; x[6]=c1.z; x[7]=c1.w;
    } else {
      uint4 cx = nh;
      if (r < 63) nh = *(const uint4*)(fbh + (size_t)(r + 1) * D_);
      x[0]=b2f(cx.x & 0xffff); x[1]=b2f(cx.x >> 16);
      x[2]=b2f(cx.y & 0xffff); x[3]=b2f(cx.y >> 16);
      x[4]=b2f(cx.z & 0xffff); x[5]=b2f(cx.z >> 16);
      x[6]=b2f(cx.w & 0xffff); x[7]=b2f(cx.w >> 16);
    }
    float sum = 0.0f;
    #pragma unroll
    for (int j = 0; j < 8; j++) sum += x[j];
    float mean = allsum64(sum) * (1.0f / 512.0f);
    float var = 0.0f;
    #pragma unroll
    for (int j = 0; j < 8; j++){ x[j] -= mean; var += x[j] * x[j]; }
    var = allsum64(var) * (1.0f / 512.0f);
    float rstd = 1.0f / sqrtf(var + LN_EPS);
    float y[8];
    #pragma unroll
    for (int j = 0; j < 8; j++) y[j] = x[j] * rstd * lw[j] + lb[j];

    float dt[8];
    #pragma unroll
    for (int s = 0; s < 8; s++){
      float t = 0.0f;
      #pragma unroll
      for (int j = 0; j < 8; j++) t += qkr[s][j] * y[j];
      dt[s] = allsum64(t) * SCALE_;
    }
    float mx = dt[0];
    #pragma unroll
    for (int s = 1; s < 8; s++) mx = fmaxf(mx, dt[s]);
    float p[8]; float den = 0.0f;
    #pragma unroll
    for (int s = 0; s < 8; s++){ p[s] = __expf(dt[s] - mx); den += p[s]; }
    float inv = 1.0f / den;
    #pragma unroll
    for (int s = 0; s < 8; s++) p[s] *= inv;
    #pragma unroll
    for (int s = 0; s < 8; s++) if (lane == s) pbuf[s][wid * 64 + r] = p[s];
    #pragma unroll
    for (int s = 0; s < 8; s++){
      float pe = p[s] + EPS_;
      racc[s] += pe;
      #pragma unroll
      for (int j = 0; j < 8; j++) U[s][j] += pe * y[j];
    }
  }
  #pragma unroll
  for (int s = 0; s < 8; s++){
    float* ub = &Ubuf[wid][s * D_ + 8 * lane];
    *(float4*)ub     = make_float4(U[s][0], U[s][1], U[s][2], U[s][3]);
    *(float4*)(ub+4) = make_float4(U[s][4], U[s][5], U[s][6], U[s][7]);
  }
  #pragma unroll
  for (int s = 0; s < 8; s++) if (lane == s) Rbuf[wid][s] = racc[s];
  __syncthreads();
  float* up = Upart + (size_t)(b * 16 + blockIdx.x) * S_ * D_;
  for (int e = tid; e < S_ * D_; e += 256)
    up[e] = Ubuf[0][e] + Ubuf[1][e] + Ubuf[2][e] + Ubuf[3][e];
  if (tid < 8)
    Rpart[(b * 16 + blockIdx.x) * S_ + tid] =
        Rbuf[0][tid] + Rbuf[1][tid] + Rbuf[2][tid] + Rbuf[3][tid];
  #pragma unroll
  for (int s = 0; s < 8; s++){
    size_t oi = 131072 + ((size_t)(b * S_ + s)) * F_ + fblock + tid;
    float pv = pbuf[s][tid];
    if (F32) ((float*)d_out_base)[oi] = pv;
    else     ((bf16*)d_out_base)[oi] = __float2bfloat16(pv);
  }
}

__global__ __launch_bounds__(256) void reduce_updates(
    const float* __restrict__ Upart, const float* __restrict__ Rpart,
    float* __restrict__ Ud)
{
  __shared__ float rinv;
  int bs = blockIdx.x;
  int b = bs >> 3, s = bs & 7;
  int t = threadIdx.x;
  if (t == 0){
    float r = 0.0f;
    for (int w = 0; w < 16; w++) r += Rpart[(b * 16 + w) * S_ + s];
    rinv = 1.0f / r;
  }
  __syncthreads();
  const float* up = Upart + ((size_t)(b * 16) * S_ + s) * D_;
  float ri = rinv;
  #pragma unroll
  for (int u = 0; u < 2; u++){
    int e = t + u * 256;
    float acc = 0.0f;
    for (int w = 0; w < 16; w++) acc += up[(size_t)w * S_ * D_ + e];
    Ud[((size_t)(b * S_ + s)) * D_ + e] = acc * ri;
  }
}

__global__ __launch_bounds__(256) void ln_rows(
    const float* __restrict__ x, const void* __restrict__ w,
    const void* __restrict__ b, float* __restrict__ y, const int* __restrict__ flag)
{
  const bool f32 = (*flag != 0);
  __shared__ float sh[4];
  int row = blockIdx.x, t = threadIdx.x;
  const float* xr = x + (size_t)row * D_;
  float v0 = xr[t], v1 = xr[t + 256];
  float mean = blockSum256(v0 + v1, sh) * (1.0f / 512.0f);
  float d0 = v0 - mean, d1 = v1 - mean;
  float var = blockSum256(d0 * d0 + d1 * d1, sh) * (1.0f / 512.0f);
  float rstd = 1.0f / sqrtf(var + LN_EPS);
  float w0 = f32 ? ((const float*)w)[t]       : b2f(((const ushort_t*)w)[t]);
  float w1 = f32 ? ((const float*)w)[t + 256] : b2f(((const ushort_t*)w)[t + 256]);
  float b0 = f32 ? ((const float*)b)[t]       : b2f(((const ushort_t*)b)[t]);
  float b1 = f32 ? ((const float*)b)[t + 256] : b2f(((const ushort_t*)b)[t + 256]);
  y[(size_t)row * D_ + t]       = d0 * rstd * w0 + b0;
  y[(size_t)row * D_ + t + 256] = d1 * rstd * w1 + b1;
}

__global__ __launch_bounds__(256) void gru_gate_ln(
    const float* __restrict__ gi, const float* __restrict__ gh,
    const float* __restrict__ sn, const void* __restrict__ lw,
    const void* __restrict__ lb, float* __restrict__ snew,
    float* __restrict__ lnm, const int* __restrict__ flag)
{
  const bool f32 = (*flag != 0);
  __shared__ float sh[4];
  int row = blockIdx.x, t = threadIdx.x;
  const float* gir = gi + (size_t)row * 1536;
  const float* ghr = gh + (size_t)row * 1536;
  const float* snr = sn + (size_t)row * D_;
  float v[2];
  #pragma unroll
  for (int u = 0; u < 2; u++){
    int d = t + u * 256;
    float ir = gir[d], iz = gir[512 + d], in_ = gir[1024 + d];
    float hr = ghr[d], hz = ghr[512 + d], hn = ghr[1024 + d];
    float rg = 1.0f / (1.0f + __expf(-(ir + hr)));
    float zg = 1.0f / (1.0f + __expf(-(iz + hz)));
    float a  = in_ + rg * hn;
    float e2 = __expf(2.0f * a);
    float ng = 1.0f - 2.0f / (e2 + 1.0f);
    float h  = snr[d];
    v[u] = (1.0f - zg) * ng + zg * h;
    snew[(size_t)row * D_ + d] = v[u];
  }
  float mean = blockSum256(v[0] + v[1], sh) * (1.0f / 512.0f);
  float d0 = v[0] - mean, d1 = v[1] - mean;
  float var = blockSum256(d0 * d0 + d1 * d1, sh) * (1.0f / 512.0f);
  float rstd = 1.0f / sqrtf(var + LN_EPS);
  float w0 = f32 ? ((const float*)lw)[t]       : b2f(((const ushort_t*)lw)[t]);
  float w1 = f32 ? ((const float*)lw)[t + 256] : b2f(((const ushort_t*)lw)[t + 256]);
  float b0 = f32 ? ((const float*)lb)[t]       : b2f(((const ushort_t*)lb)[t]);
  float b1 = f32 ? ((const float*)lb)[t + 256] : b2f(((const ushort_t*)lb)[t + 256]);
  lnm[(size_t)row * D_ + t]       = d0 * rstd * w0 + b0;
  lnm[(size_t)row * D_ + t + 256] = d1 * rstd * w1 + b1;
}

__global__ __launch_bounds__(256) void combine_h2(
    const float* __restrict__ snew, const float* __restrict__ h2p,
    const void* __restrict__ b2, float* __restrict__ slots,
    const int* __restrict__ flag)
{
  const bool f32 = (*flag != 0);
  int idx = blockIdx.x * 256 + threadIdx.x;
  int d = idx & 511;
  float bias = f32 ? ((const float*)b2)[d] : b2f(((const ushort_t*)b2)[d]);
  slots[idx] = snew[idx] + h2p[idx] + h2p[131072 + idx] + h2p[262144 + idx]
             + h2p[393216 + idx] + bias;
}

__global__ __launch_bounds__(256) void cast_in(const void* __restrict__ in,
                                               float* __restrict__ out,
                                               const int* __restrict__ flag){
  const bool f32 = (*flag != 0);
  int i = blockIdx.x * 256 + threadIdx.x;
  out[i] = f32 ? ((const float*)in)[i] : b2f(((const ushort_t*)in)[i]);
}
__global__ __launch_bounds__(256) void store_out(const float* __restrict__ in,
                                                 void* __restrict__ out,
                                                 const int* __restrict__ flag){
  const bool f32 = (*flag != 0);
  int i = blockIdx.x * 256 + threadIdx.x;
  float v = in[i];
  if (f32) ((float*)out)[i] = v;
  else     ((bf16*)out)[i] = __float2bfloat16(v);
}

extern "C" void kernel_launch(void* const* d_in, const int* in_sizes, int n_in,
                              void* d_out, int out_size, void* d_ws, size_t ws_size,
                              hipStream_t stream)
{
  const void* in_slots  = d_in[0];
  const void* features  = d_in[1];
  const void* w_k   = d_in[2];
  const void* w_v   = d_in[3];
  const void* w_q   = d_in[4];
  const void* ln_feat_w = d_in[5];
  const void* ln_feat_b = d_in[6];
  const void* ln_slot_w = d_in[7];
  const void* ln_slot_b = d_in[8];
  const void* w_ih  = d_in[9];
  const void* w_hh  = d_in[10];
  const void* b_ih  = d_in[11];
  const void* b_hh  = d_in[12];
  const void* ln_mlp_w = d_in[13];
  const void* ln_mlp_b = d_in[14];
  const void* mlp_w1 = d_in[15];
  const void* mlp_b1 = d_in[16];
  const void* mlp_w2 = d_in[17];
  const void* mlp_b2 = d_in[18];

  // round-2 layout, unchanged
  float* W     = (float*)d_ws;
  int*   flag  = (int*)d_ws;
  float* Wqk   = W + 64;
  float* slots = Wqk + 262144;
  float* s_n   = slots + 131072;
  float* qkb   = s_n + 131072;
  float* Ud    = qkb + 131072;
  float* upd   = Ud + 131072;
  float* Rpart = upd + 131072;
  float* P     = Rpart + 4096;     // union region (2097152 floats)
  float* Upart = P;                // dead after reduce_updates
  float* gi    = P;
  float* gh    = P + 393216;
  float* lnm   = P + 786432;
  float* snew  = P + 917504;
  float* h1    = P + 1048576;
  float* h2p   = P + 1572864;
  // NEW: split-K partial buffers appended after the round-2 region
  float* Wqkp  = P + 2097152;      // 4 x 262144
  float* qkp   = Wqkp + 1048576;   // 4 x 131072
  float* updp  = qkp + 524288;     // 4 x 131072
  float* gip   = updp + 524288;    // 4 x 393216
  float* ghp   = gip + 1572864;    // 4 x 393216
  float* h1p   = ghp + 1572864;    // 4 x 524288  -> end ~41 MB

  detect_dtype<<<1, 256, 0, stream>>>((const uint32_t*)features, flag);
  cast_in<<<512, 256, 0, stream>>>(in_slots, slots, flag);
  // Wqk = w_q @ w_k^T, split-K 4 + combine
  gemm64<1, 0, 0, 1, 1><<<dim3(8, 8, 4), 256, 0, stream>>>(
      w_q, w_k, nullptr, Wqkp, 512, 512, 512, 128, flag);
  combine4<0, 0><<<1024, 256, 0, stream>>>(Wqkp, nullptr, Wqk, 262144, 512);

  for (int it = 0; it < 3; ++it){
    ln_rows<<<256, 256, 0, stream>>>(slots, ln_slot_w, ln_slot_b, s_n, flag);
    // qk = s_n @ Wqk, split-K 4 + combine
    gemm64<0, 0, 0, 0, 0><<<dim3(4, 8, 4), 256, 0, stream>>>(
        s_n, Wqk, nullptr, qkp, 256, 512, 512, 128, flag);
    combine4<0, 0><<<512, 256, 0, stream>>>(qkp, nullptr, qkb, 131072, 512);
    big_pass<0><<<dim3(16, 32), 256, 0, stream>>>(
        features, qkb, ln_feat_w, ln_feat_b, d_out, Upart, Rpart, flag);
    big_pass<1><<<dim3(16, 32), 256, 0, stream>>>(
        features, qkb, ln_feat_w, ln_feat_b, d_out, Upart, Rpart, flag);
    reduce_updates<<<256, 256, 0, stream>>>(Upart, Rpart, Ud);
    // upd = Ud @ w_v, split-K 4 + combine
    gemm64<0, 0, 0, 0, 1><<<dim3(4, 8, 4), 256, 0, stream>>>(
        Ud, w_v, nullptr, updp, 256, 512, 512, 128, flag);
    combine4<0, 0><<<512, 256, 0, stream>>>(updp, nullptr, upd, 131072, 512);
    // gi = upd @ w_ih^T + b_ih, split-K 4 + combine(bias)
    gemm64<1, 0, 0, 0, 1><<<dim3(4, 24, 4), 256, 0, stream>>>(
        upd, w_ih, nullptr, gip, 256, 1536, 512, 128, flag);
    combine4<1, 0><<<1536, 256, 0, stream>>>(gip, b_ih, gi, 393216, 1536);
    // gh = s_n @ w_hh^T + b_hh, split-K 4 + combine(bias)
    gemm64<1, 0, 0, 0, 1><<<dim3(4, 24, 4), 256, 0, stream>>>(
        s_n, w_hh, nullptr, ghp, 256, 1536, 512, 128, flag);
    combine4<1, 0><<<1536, 256, 0, stream>>>(ghp, b_hh, gh, 393216, 1536);
    gru_gate_ln<<<256, 256, 0, stream>>>(gi, gh, s_n, ln_mlp_w, ln_mlp_b,
                                         snew, lnm, flag);
    // h1 = relu(lnm @ mlp_w1 + b1), split-K 4 + combine(bias, relu)
    gemm64<0, 0, 0, 0, 1><<<dim3(4, 32, 4), 256, 0, stream>>>(
        lnm, mlp_w1, nullptr, h1p, 256, 2048, 512, 128, flag);
    combine4<1, 1><<<2048, 256, 0, stream>>>(h1p, mlp_b1, h1, 524288, 2048);
    // h2 partials = h1 @ mlp_w2 (unchanged from round 2: split-K 4)
    gemm64<0, 0, 0, 0, 1><<<dim3(4, 8, 4), 256, 0, stream>>>(
        h1, mlp_w2, nullptr, h2p, 256, 512, 2048, 512, flag);
    combine_h2<<<512, 256, 0, stream>>>(snew, h2p, mlp_b2, slots, flag);
  }
  store_out<<<512, 256, 0, stream>>>(slots, d_out, flag);
}